// Round 1
// baseline (352.084 us; speedup 1.0000x reference)
//
#include <hip/hip_runtime.h>
#include <hip/hip_bf16.h>
#include <stdint.h>

#define B_ 8
#define S_ 1024
#define NV_ 768
#define D_ 512
#define DF_ 2048
#define H_ 8
#define DH_ 64
#define BS_ (B_*S_)
#define BSD_ ((size_t)B_*S_*D_)

typedef __bf16 bf16x8 __attribute__((ext_vector_type(8)));
typedef float f32x4 __attribute__((ext_vector_type(4)));
typedef __hip_bfloat16 bf16;

__device__ __forceinline__ void async_copy16(const void* g, void* l) {
  __builtin_amdgcn_global_load_lds((const __attribute__((address_space(1))) void*)g,
                                   (__attribute__((address_space(3))) void*)l, 16, 0, 0);
}

__device__ __forceinline__ unsigned short f2bu(float f) {
  bf16 h = __float2bfloat16(f);
  return *reinterpret_cast<unsigned short*>(&h);
}

// Stage a tile of `rows` x 64 bf16 columns into LDS.
// LDS layout: row-major 128B rows, XOR-swizzled byte ^= (row&7)<<4 to kill
// bank conflicts on ds_read_b128 fragment reads. global_load_lds writes LDS
// linearly, so the swizzle is pre-applied to the GLOBAL source address
// (rule 21: linear dest + inverse-swizzled source + swizzled read).
__device__ __forceinline__ void stage_tile(const bf16* __restrict__ g, int gRow0, long ldg,
                                           int gCol0, bf16* lds, int rows, int tid) {
  const int totalBytes = rows << 7;
  for (int off = tid * 16; off < totalBytes; off += 4096) {
    const int r = off >> 7;
    const int c = off & 127;
    const int srcByte = c ^ ((r & 7) << 4);
    const bf16* gp = g + (long)(gRow0 + r) * ldg + gCol0 + (srcByte >> 1);
    async_copy16(gp, (char*)lds + off);
  }
}

// Read an 8-element (16B) MFMA fragment: element (row, kElem..kElem+7)
__device__ __forceinline__ bf16x8 lds_frag(const bf16* base, int row, int kElem) {
  const int byte = (row << 7) + ((kElem << 1) ^ ((row & 7) << 4));
  return *(const bf16x8*)((const char*)base + byte);
}

// ---------- weight transpose+convert: src fp32 [K][N] -> dst bf16 [N][K] ----------
__global__ __launch_bounds__(256) void wtrans_kernel(const float* __restrict__ src,
                                                     bf16* __restrict__ dst, int K, int N) {
  __shared__ float tile[32][33];
  const int tx = threadIdx.x, ty = threadIdx.y;
  const int n0 = blockIdx.x * 32, k0 = blockIdx.y * 32;
#pragma unroll
  for (int i = 0; i < 4; i++) tile[ty + i * 8][tx] = src[(long)(k0 + ty + i * 8) * N + n0 + tx];
  __syncthreads();
#pragma unroll
  for (int i = 0; i < 4; i++)
    dst[(long)(n0 + ty + i * 8) * K + k0 + tx] = __float2bfloat16(tile[tx][ty + i * 8]);
}

// ---------- V transpose: (B,S,H,DH) bf16 -> (B,H,DH,S) bf16 ----------
__global__ __launch_bounds__(256) void vtrans_kernel(const bf16* __restrict__ src,
                                                     bf16* __restrict__ dst) {
  __shared__ bf16 tile[32][33];
  const int tx = threadIdx.x, ty = threadIdx.y;
  const int s0 = blockIdx.x * 32, d0 = blockIdx.y * 32;
  const int bh = blockIdx.z;
  const int b = bh >> 3, h = bh & 7;
  const bf16* sp = src + (long)b * S_ * D_ + h * DH_;
  bf16* dp = dst + (long)bh * DH_ * S_;
#pragma unroll
  for (int i = 0; i < 4; i++) tile[ty + i * 8][tx] = sp[(long)(s0 + ty + i * 8) * D_ + d0 + tx];
  __syncthreads();
#pragma unroll
  for (int i = 0; i < 4; i++) dp[(long)(d0 + ty + i * 8) * S_ + s0 + tx] = tile[tx][ty + i * 8];
}

// ---------- gather + fp32->bf16: x_l1[b,s] = x[b, s<N? idx[b,s] : s] ----------
__global__ __launch_bounds__(256) void gather_cvt_kernel(const float* __restrict__ x,
                                                         const int* __restrict__ idx,
                                                         const int* __restrict__ Np,
                                                         bf16* __restrict__ out) {
  const int N = *Np;
  const int row = blockIdx.x * 2 + (threadIdx.x >> 7);
  const int t = threadIdx.x & 127;
  const int b = row >> 10, s = row & 1023;
  const int src = (s < N) ? idx[b * NV_ + s] : s;
  const float4 v = *(const float4*)(x + ((long)b * S_ + src) * D_ + t * 4);
  ushort4 u;
  u.x = f2bu(v.x); u.y = f2bu(v.y); u.z = f2bu(v.z); u.w = f2bu(v.w);
  *(ushort4*)(out + (long)row * D_ + t * 4) = u;
}

// ---------- GEMM: C[M,N] = A[M,K] * Bt[N,K]^T (+bias)(+relu), 128x128 tile ----------
template<int OUTF, int BIAS, int RELU>
__global__ __launch_bounds__(256) void gemm_bt_kernel(const bf16* __restrict__ A,
                                                      const bf16* __restrict__ Bt,
                                                      const float* __restrict__ bias,
                                                      void* __restrict__ Cout,
                                                      int M, int N, int K) {
  __shared__ bf16 As[128 * 64];
  __shared__ bf16 Bs[128 * 64];
  const int tid = threadIdx.x;
  const int lane = tid & 63, wave = tid >> 6;
  const int wr = wave >> 1, wc = wave & 1;
  const int g = lane >> 4, lr = lane & 15;
  const int m0 = blockIdx.x * 128, n0 = blockIdx.y * 128;

  f32x4 acc[4][4];
#pragma unroll
  for (int m = 0; m < 4; m++)
#pragma unroll
    for (int n = 0; n < 4; n++) acc[m][n] = (f32x4){0.f, 0.f, 0.f, 0.f};

  for (int kt = 0; kt < K; kt += 64) {
    stage_tile(A, m0, K, kt, As, 128, tid);
    stage_tile(Bt, n0, K, kt, Bs, 128, tid);
    __syncthreads();
#pragma unroll
    for (int ks = 0; ks < 64; ks += 32) {
      const int kk = ks + g * 8;
      bf16x8 aF[4], bF[4];
#pragma unroll
      for (int m = 0; m < 4; m++) aF[m] = lds_frag(As, wr * 64 + m * 16 + lr, kk);
#pragma unroll
      for (int n = 0; n < 4; n++) bF[n] = lds_frag(Bs, wc * 64 + n * 16 + lr, kk);
#pragma unroll
      for (int m = 0; m < 4; m++)
#pragma unroll
        for (int n = 0; n < 4; n++)
          acc[m][n] = __builtin_amdgcn_mfma_f32_16x16x32_bf16(aF[m], bF[n], acc[m][n], 0, 0, 0);
    }
    __syncthreads();
  }

#pragma unroll
  for (int m = 0; m < 4; m++) {
#pragma unroll
    for (int n = 0; n < 4; n++) {
      const int row = m0 + wr * 64 + m * 16 + g * 4;   // C/D: row = 4*(lane>>4)+reg
      const int col = n0 + wc * 64 + n * 16 + lr;      //      col = lane&15
      const float bv = BIAS ? bias[col] : 0.f;
#pragma unroll
      for (int r = 0; r < 4; r++) {
        float v = acc[m][n][r] + bv;
        if (RELU) v = fmaxf(v, 0.f);
        if (OUTF) ((float*)Cout)[(long)(row + r) * N + col] = v;
        else ((bf16*)Cout)[(long)(row + r) * N + col] = __float2bfloat16(v);
      }
    }
  }
}

// ---------- flash attention: 1 block per (b,h,qtile64); Vt is (B,H,DH,S) ----------
__global__ __launch_bounds__(256) void flash_kernel(const bf16* __restrict__ Q,
                                                    const bf16* __restrict__ Kmat,
                                                    const bf16* __restrict__ Vt,
                                                    bf16* __restrict__ O) {
  __shared__ bf16 Qs[64 * 64], Ks[64 * 64], Vs[64 * 64];
  __shared__ bf16 Ps[4][16 * 64];
  const int tid = threadIdx.x;
  const int lane = tid & 63, wave = tid >> 6;
  const int g = lane >> 4, lr = lane & 15;
  const int qt = blockIdx.x & 15;       // S/64 = 16
  const int bh = blockIdx.x >> 4;
  const int b = bh >> 3, h = bh & 7;

  const bf16* Qp = Q + (long)b * S_ * D_ + h * DH_;
  const bf16* Kp = Kmat + (long)b * S_ * D_ + h * DH_;
  const bf16* Vp = Vt + (long)bh * DH_ * S_;

  stage_tile(Qp, qt * 64, D_, 0, Qs, 64, tid);

  f32x4 oAcc[4];
#pragma unroll
  for (int n = 0; n < 4; n++) oAcc[n] = (f32x4){0.f, 0.f, 0.f, 0.f};
  float mrun[4], lrun[4];
#pragma unroll
  for (int r = 0; r < 4; r++) { mrun[r] = -INFINITY; lrun[r] = 0.f; }

  for (int kt0 = 0; kt0 < S_; kt0 += 64) {
    stage_tile(Kp, kt0, D_, 0, Ks, 64, tid);
    stage_tile(Vp, 0, S_, kt0, Vs, 64, tid);
    __syncthreads();

    f32x4 sAcc[4];
#pragma unroll
    for (int n = 0; n < 4; n++) sAcc[n] = (f32x4){0.f, 0.f, 0.f, 0.f};
#pragma unroll
    for (int ks = 0; ks < 64; ks += 32) {
      bf16x8 qF = lds_frag(Qs, wave * 16 + lr, ks + g * 8);
#pragma unroll
      for (int n = 0; n < 4; n++) {
        bf16x8 kF = lds_frag(Ks, n * 16 + lr, ks + g * 8);
        sAcc[n] = __builtin_amdgcn_mfma_f32_16x16x32_bf16(qF, kF, sAcc[n], 0, 0, 0);
      }
    }

    const float sc = 0.125f;  // 1/sqrt(DH)
    float p[4][4];
#pragma unroll
    for (int r = 0; r < 4; r++) {
      float mx = fmaxf(fmaxf(sAcc[0][r], sAcc[1][r]), fmaxf(sAcc[2][r], sAcc[3][r])) * sc;
#pragma unroll
      for (int d = 1; d < 16; d <<= 1) mx = fmaxf(mx, __shfl_xor(mx, d, 64));
      const float mnew = fmaxf(mrun[r], mx);
      const float resc = __expf(mrun[r] - mnew);
      mrun[r] = mnew;
#pragma unroll
      for (int n = 0; n < 4; n++) oAcc[n][r] *= resc;
      float s = 0.f;
#pragma unroll
      for (int n = 0; n < 4; n++) {
        const float pv = __expf(sAcc[n][r] * sc - mnew);
        p[n][r] = pv; s += pv;
      }
#pragma unroll
      for (int d = 1; d < 16; d <<= 1) s += __shfl_xor(s, d, 64);
      lrun[r] = lrun[r] * resc + s;
    }

    // P -> per-wave LDS (bf16), same XOR swizzle so reads are conflict-light
    bf16* Pw = Ps[wave];
#pragma unroll
    for (int n = 0; n < 4; n++)
#pragma unroll
      for (int r = 0; r < 4; r++) {
        const int q = g * 4 + r;
        const int key = n * 16 + lr;
        const int byte = (q << 7) + ((key << 1) ^ ((q & 7) << 4));
        *(bf16*)((char*)Pw + byte) = __float2bfloat16(p[n][r]);
      }

    // PV: A = P[16 q][64 key], B = Vt tile [64 d][64 key]
#pragma unroll
    for (int ks = 0; ks < 64; ks += 32) {
      bf16x8 pF = lds_frag(Pw, lr, ks + g * 8);
#pragma unroll
      for (int n = 0; n < 4; n++) {
        bf16x8 vF = lds_frag(Vs, n * 16 + lr, ks + g * 8);
        oAcc[n] = __builtin_amdgcn_mfma_f32_16x16x32_bf16(pF, vF, oAcc[n], 0, 0, 0);
      }
    }
    __syncthreads();
  }

#pragma unroll
  for (int r = 0; r < 4; r++) {
    const float inv = 1.f / lrun[r];
    const int s = qt * 64 + wave * 16 + g * 4 + r;
    bf16* op = O + ((long)b * S_ + s) * D_ + h * DH_;
#pragma unroll
    for (int n = 0; n < 4; n++) op[n * 16 + lr] = __float2bfloat16(oAcc[n][r] * inv);
  }
}

// ---------- fuse1: xln = LN(x + gather(attn1+attn2)) ; write fp32 + bf16 ----------
__global__ __launch_bounds__(256) void fuse1_kernel(const float* __restrict__ x,
                                                    const float* __restrict__ a1,
                                                    const float* __restrict__ a2,
                                                    const int* __restrict__ idx,
                                                    const int* __restrict__ Np,
                                                    const float* __restrict__ gw,
                                                    const float* __restrict__ bw,
                                                    float* __restrict__ xlnF,
                                                    bf16* __restrict__ xlnB) {
  const int N = *Np;
  const int row = blockIdx.x * 4 + (threadIdx.x >> 6);
  const int lane = threadIdx.x & 63;
  const int b = row >> 10, s = row & 1023;
  const int j = (s < N) ? idx[b * NV_ + s] : s;
  const float* xp = x + (long)row * D_;
  const float* p1 = a1 + ((long)b * S_ + j) * D_;
  const float* p2 = a2 + ((long)b * S_ + j) * D_;
  float v[8];
  float sum = 0.f;
#pragma unroll
  for (int i = 0; i < 8; i++) {
    const int d = lane + i * 64;
    v[i] = xp[d] + p1[d] + p2[d];
    sum += v[i];
  }
#pragma unroll
  for (int o = 1; o < 64; o <<= 1) sum += __shfl_xor(sum, o, 64);
  const float mu = sum * (1.f / D_);
  float var = 0.f;
#pragma unroll
  for (int i = 0; i < 8; i++) { const float t = v[i] - mu; var += t * t; }
#pragma unroll
  for (int o = 1; o < 64; o <<= 1) var += __shfl_xor(var, o, 64);
  const float rs = rsqrtf(var * (1.f / D_) + 1e-5f);
#pragma unroll
  for (int i = 0; i < 8; i++) {
    const int d = lane + i * 64;
    const float o = (v[i] - mu) * rs * gw[d] + bw[d];
    xlnF[(long)row * D_ + d] = o;
    xlnB[(long)row * D_ + d] = __float2bfloat16(o);
  }
}

// ---------- fuse2: out = LN(xln + y) ----------
__global__ __launch_bounds__(256) void fuse2_kernel(const float* __restrict__ xlnF,
                                                    const bf16* __restrict__ ybf,
                                                    const float* __restrict__ gw,
                                                    const float* __restrict__ bw,
                                                    float* __restrict__ out) {
  const int row = blockIdx.x * 4 + (threadIdx.x >> 6);
  const int lane = threadIdx.x & 63;
  const float* xp = xlnF + (long)row * D_;
  const bf16* yp = ybf + (long)row * D_;
  float v[8];
  float sum = 0.f;
#pragma unroll
  for (int i = 0; i < 8; i++) {
    const int d = lane + i * 64;
    v[i] = xp[d] + __bfloat162float(yp[d]);
    sum += v[i];
  }
#pragma unroll
  for (int o = 1; o < 64; o <<= 1) sum += __shfl_xor(sum, o, 64);
  const float mu = sum * (1.f / D_);
  float var = 0.f;
#pragma unroll
  for (int i = 0; i < 8; i++) { const float t = v[i] - mu; var += t * t; }
#pragma unroll
  for (int o = 1; o < 64; o <<= 1) var += __shfl_xor(var, o, 64);
  const float rs = rsqrtf(var * (1.f / D_) + 1e-5f);
#pragma unroll
  for (int i = 0; i < 8; i++) {
    const int d = lane + i * 64;
    out[(long)row * D_ + d] = (v[i] - mu) * rs * gw[d] + bw[d];
  }
}

extern "C" void kernel_launch(void* const* d_in, const int* in_sizes, int n_in,
                              void* d_out, int out_size, void* d_ws, size_t ws_size,
                              hipStream_t stream) {
  const float* x   = (const float*)d_in[0];
  const int* idx1  = (const int*)d_in[1];
  const int* idx2  = (const int*)d_in[2];
  const int* Np    = (const int*)d_in[3];
  const float* Wq1 = (const float*)d_in[4];
  const float* Wk1 = (const float*)d_in[5];
  const float* Wv1 = (const float*)d_in[6];
  const float* Wo1 = (const float*)d_in[7];
  const float* Wq2 = (const float*)d_in[8];
  const float* Wk2 = (const float*)d_in[9];
  const float* Wv2 = (const float*)d_in[10];
  const float* Wo2 = (const float*)d_in[11];
  const float* w_conv1 = (const float*)d_in[12];
  const float* b_conv1 = (const float*)d_in[13];
  const float* w_conv2 = (const float*)d_in[14];
  const float* b_conv2 = (const float*)d_in[15];
  const float* g1    = (const float*)d_in[16];
  const float* beta1 = (const float*)d_in[17];
  const float* g2    = (const float*)d_in[18];
  const float* beta2 = (const float*)d_in[19];

  float* outp  = (float*)d_out;
  float* attn1 = outp + BSD_;
  float* attn2 = outp + 2 * BSD_;

  // workspace layout (bytes): 72 MB total
  const size_t DD = (size_t)D_ * D_;
  bf16* wT   = (bf16*)d_ws;                         // 10 transposed bf16 weights, 8.39MB
  bf16* WT[8]; for (int i = 0; i < 8; i++) WT[i] = wT + i * DD;
  bf16* w1T  = wT + 8 * DD;                         // [DF][D]
  bf16* w2T  = w1T + (size_t)DF_ * D_;              // [D][DF]
  bf16* xl1  = (bf16*)((char*)d_ws + 8388608);      // 8.39MB (later: y_bf)
  bf16* qb   = (bf16*)((char*)d_ws + 16777216);     // 4 x 8.39MB region (later: ffn hidden)
  bf16* kb   = qb + BSD_;
  bf16* vb   = kb + BSD_;                           // v, then flash O
  bf16* vtb  = vb + BSD_;                           // V^T
  float* xlnF = (float*)((char*)d_ws + 50331648);   // 16.78MB
  bf16* xlnB = (bf16*)((char*)d_ws + 67108864);     // 8.39MB
  bf16* ffn  = qb;                                  // 8192x2048 bf16 = 33.55MB (spans q..vt)
  bf16* ybf  = xl1;

  const dim3 tb(32, 8);
  // weight transposes (fp32 [K][N] -> bf16 [N][K])
  wtrans_kernel<<<dim3(D_/32, D_/32), tb, 0, stream>>>(Wq1, WT[0], D_, D_);
  wtrans_kernel<<<dim3(D_/32, D_/32), tb, 0, stream>>>(Wk1, WT[1], D_, D_);
  wtrans_kernel<<<dim3(D_/32, D_/32), tb, 0, stream>>>(Wv1, WT[2], D_, D_);
  wtrans_kernel<<<dim3(D_/32, D_/32), tb, 0, stream>>>(Wo1, WT[3], D_, D_);
  wtrans_kernel<<<dim3(D_/32, D_/32), tb, 0, stream>>>(Wq2, WT[4], D_, D_);
  wtrans_kernel<<<dim3(D_/32, D_/32), tb, 0, stream>>>(Wk2, WT[5], D_, D_);
  wtrans_kernel<<<dim3(D_/32, D_/32), tb, 0, stream>>>(Wv2, WT[6], D_, D_);
  wtrans_kernel<<<dim3(D_/32, D_/32), tb, 0, stream>>>(Wo2, WT[7], D_, D_);
  wtrans_kernel<<<dim3(DF_/32, D_/32), tb, 0, stream>>>(w_conv1, w1T, D_, DF_);
  wtrans_kernel<<<dim3(D_/32, DF_/32), tb, 0, stream>>>(w_conv2, w2T, DF_, D_);

  gather_cvt_kernel<<<BS_/2, 256, 0, stream>>>(x, idx1, Np, xl1);

  // attn2 == MHA(x_l1, set2): flip(MHA(flip(x))) == MHA(x) by permutation equivariance
  for (int set = 0; set < 2; set++) {
    const bf16* WqT = WT[set * 4 + 0];
    const bf16* WkT = WT[set * 4 + 1];
    const bf16* WvT = WT[set * 4 + 2];
    const bf16* WoT = WT[set * 4 + 3];
    float* attn = set ? attn2 : attn1;
    gemm_bt_kernel<0,0,0><<<dim3(BS_/128, D_/128), 256, 0, stream>>>(xl1, WqT, nullptr, qb, BS_, D_, D_);
    gemm_bt_kernel<0,0,0><<<dim3(BS_/128, D_/128), 256, 0, stream>>>(xl1, WkT, nullptr, kb, BS_, D_, D_);
    gemm_bt_kernel<0,0,0><<<dim3(BS_/128, D_/128), 256, 0, stream>>>(xl1, WvT, nullptr, vb, BS_, D_, D_);
    vtrans_kernel<<<dim3(S_/32, DH_/32, B_*H_), tb, 0, stream>>>(vb, vtb);
    flash_kernel<<<B_*H_*(S_/64), 256, 0, stream>>>(qb, kb, vtb, vb);  // O -> vb
    gemm_bt_kernel<1,0,0><<<dim3(BS_/128, D_/128), 256, 0, stream>>>(vb, WoT, nullptr, attn, BS_, D_, D_);
  }

  fuse1_kernel<<<BS_/4, 256, 0, stream>>>(x, attn1, attn2, idx2, Np, g1, beta1, xlnF, xlnB);
  gemm_bt_kernel<0,1,1><<<dim3(BS_/128, DF_/128), 256, 0, stream>>>(xlnB, w1T, b_conv1, ffn, BS_, DF_, D_);
  gemm_bt_kernel<0,1,0><<<dim3(BS_/128, D_/128), 256, 0, stream>>>(ffn, w2T, b_conv2, ybf, BS_, D_, DF_);
  fuse2_kernel<<<BS_/4, 256, 0, stream>>>(xlnF, ybf, g2, beta2, outp);
}

// Round 2
// 265.354 us; speedup vs baseline: 1.3268x; 1.3268x over previous
//
#include <hip/hip_runtime.h>
#include <hip/hip_bf16.h>
#include <stdint.h>

#define B_ 8
#define S_ 1024
#define NV_ 768
#define D_ 512
#define DF_ 2048
#define H_ 8
#define DH_ 64
#define BS_ (B_*S_)
#define BSD_ ((size_t)B_*S_*D_)
#define QKVLD 3072

typedef __bf16 bf16x8 __attribute__((ext_vector_type(8)));
typedef float f32x4 __attribute__((ext_vector_type(4)));
typedef __hip_bfloat16 bf16;

__device__ __forceinline__ void async_copy16(const void* g, void* l) {
  __builtin_amdgcn_global_load_lds((const __attribute__((address_space(1))) void*)g,
                                   (__attribute__((address_space(3))) void*)l, 16, 0, 0);
}

// Stage a tile of `rows` x 64 bf16 columns into LDS (row-major 128B rows).
// XOR swizzle byte ^= (row&7)<<4 applied on the GLOBAL source address
// (linear LDS dest + inverse-swizzled source + swizzled read).
__device__ __forceinline__ void stage_tile(const bf16* __restrict__ g, int gRow0, long ldg,
                                           int gCol0, bf16* lds, int rows, int tid) {
  const int totalBytes = rows << 7;
  for (int off = tid * 16; off < totalBytes; off += 4096) {
    const int r = off >> 7;
    const int c = off & 127;
    const int srcByte = c ^ ((r & 7) << 4);
    const bf16* gp = g + (long)(gRow0 + r) * ldg + gCol0 + (srcByte >> 1);
    async_copy16(gp, (char*)lds + off);
  }
}

// Read an 8-element (16B) MFMA fragment at (row, kElem..kElem+7)
__device__ __forceinline__ bf16x8 lds_frag(const bf16* base, int row, int kElem) {
  const int byte = (row << 7) + ((kElem << 1) ^ ((row & 7) << 4));
  return *(const bf16x8*)((const char*)base + byte);
}

// ---------- 8x weight transpose+convert (512x512): src fp32 [K][N] -> bf16 [N][K] ----------
struct WP8 { const float* p[8]; };
__global__ __launch_bounds__(256) void wtrans8_kernel(WP8 ws, bf16* __restrict__ dstBase) {
  __shared__ float tile[32][33];
  const float* __restrict__ src = ws.p[blockIdx.z];
  bf16* __restrict__ dst = dstBase + (size_t)blockIdx.z * D_ * D_;
  const int tx = threadIdx.x, ty = threadIdx.y;
  const int n0 = blockIdx.x * 32, k0 = blockIdx.y * 32;
#pragma unroll
  for (int i = 0; i < 4; i++) tile[ty + i * 8][tx] = src[(long)(k0 + ty + i * 8) * D_ + n0 + tx];
  __syncthreads();
#pragma unroll
  for (int i = 0; i < 4; i++)
    dst[(long)(n0 + ty + i * 8) * D_ + k0 + tx] = __float2bfloat16(tile[tx][ty + i * 8]);
}

// ---------- generic weight transpose+convert ----------
__global__ __launch_bounds__(256) void wtrans_kernel(const float* __restrict__ src,
                                                     bf16* __restrict__ dst, int K, int N) {
  __shared__ float tile[32][33];
  const int tx = threadIdx.x, ty = threadIdx.y;
  const int n0 = blockIdx.x * 32, k0 = blockIdx.y * 32;
#pragma unroll
  for (int i = 0; i < 4; i++) tile[ty + i * 8][tx] = src[(long)(k0 + ty + i * 8) * N + n0 + tx];
  __syncthreads();
#pragma unroll
  for (int i = 0; i < 4; i++)
    dst[(long)(n0 + ty + i * 8) * K + k0 + tx] = __float2bfloat16(tile[tx][ty + i * 8]);
}

// ---------- V transpose out of qkv: cols (set*1536+1024+h*64 ..+64) -> (set,b,h)[DH][S] ----------
__global__ __launch_bounds__(256) void vtrans_kernel(const bf16* __restrict__ qkv,
                                                     bf16* __restrict__ vtb) {
  __shared__ bf16 tile[32][33];
  const int tx = threadIdx.x, ty = threadIdx.y;
  const int s0 = blockIdx.x * 32, d0 = blockIdx.y * 32;
  const int z = blockIdx.z;               // 0..127: set*64 + b*8 + h
  const int set = z >> 6, bh = z & 63;
  const bf16* sp = qkv + (long)(bh >> 3) * S_ * QKVLD + set * 1536 + 1024 + (bh & 7) * 64;
  bf16* dp = vtb + (long)z * DH_ * S_;
#pragma unroll
  for (int i = 0; i < 4; i++) tile[ty + i * 8][tx] = sp[(long)(s0 + ty + i * 8) * QKVLD + d0 + tx];
  __syncthreads();
#pragma unroll
  for (int i = 0; i < 4; i++) dp[(long)(d0 + ty + i * 8) * S_ + s0 + tx] = tile[tx][ty + i * 8];
}

// ---------- gather + fp32->bf16 ----------
__global__ __launch_bounds__(256) void gather_cvt_kernel(const float* __restrict__ x,
                                                         const int* __restrict__ idx,
                                                         const int* __restrict__ Np,
                                                         bf16* __restrict__ out) {
  const int N = *Np;
  const int row = blockIdx.x * 2 + (threadIdx.x >> 7);
  const int t = threadIdx.x & 127;
  const int b = row >> 10, s = row & 1023;
  const int src = (s < N) ? idx[b * NV_ + s] : s;
  const float4 v = *(const float4*)(x + ((long)b * S_ + src) * D_ + t * 4);
  ushort4 u;
  u.x = (ushort)__bfloat16_as_ushort(__float2bfloat16(v.x));
  u.y = (ushort)__bfloat16_as_ushort(__float2bfloat16(v.y));
  u.z = (ushort)__bfloat16_as_ushort(__float2bfloat16(v.z));
  u.w = (ushort)__bfloat16_as_ushort(__float2bfloat16(v.w));
  *(ushort4*)(out + (long)row * D_ + t * 4) = u;
}

// ---------- GEMM: C[M,N] = A[M,K] * Bt[N,K]^T (+bias)(+relu) ----------
template<int BM, int BN, int MR, int NR, int OUTF, int BIAS, int RELU>
__global__ __launch_bounds__(256) void gemm_bt(const bf16* __restrict__ A, long lda, long sAz,
                                               const bf16* __restrict__ Bt, long sBz,
                                               const float* __restrict__ bias,
                                               void* __restrict__ C, long ldc, long sCz,
                                               int K) {
  constexpr int WC = BN / (NR * 16);
  constexpr int WR = BM / (MR * 16);
  static_assert(WR * WC == 4, "4 waves");
  __shared__ bf16 As[BM * 64];
  __shared__ bf16 Bs[BN * 64];
  const int tid = threadIdx.x;
  const int lane = tid & 63, wave = tid >> 6;
  const int wr = wave / WC, wc = wave % WC;
  const int g = lane >> 4, lr = lane & 15;
  const int m0 = blockIdx.x * BM, n0 = blockIdx.y * BN;
  const int z = blockIdx.z;
  A += (long)z * sAz;
  Bt += (long)z * sBz;

  f32x4 acc[MR][NR];
#pragma unroll
  for (int m = 0; m < MR; m++)
#pragma unroll
    for (int n = 0; n < NR; n++) acc[m][n] = (f32x4){0.f, 0.f, 0.f, 0.f};

  for (int kt = 0; kt < K; kt += 64) {
    stage_tile(A, m0, lda, kt, As, BM, tid);
    stage_tile(Bt, n0, K, kt, Bs, BN, tid);
    __syncthreads();
#pragma unroll
    for (int ks = 0; ks < 64; ks += 32) {
      const int kk = ks + g * 8;
      bf16x8 aF[MR], bF[NR];
#pragma unroll
      for (int m = 0; m < MR; m++) aF[m] = lds_frag(As, wr * (MR * 16) + m * 16 + lr, kk);
#pragma unroll
      for (int n = 0; n < NR; n++) bF[n] = lds_frag(Bs, wc * (NR * 16) + n * 16 + lr, kk);
#pragma unroll
      for (int m = 0; m < MR; m++)
#pragma unroll
        for (int n = 0; n < NR; n++)
          acc[m][n] = __builtin_amdgcn_mfma_f32_16x16x32_bf16(aF[m], bF[n], acc[m][n], 0, 0, 0);
    }
    __syncthreads();
  }

#pragma unroll
  for (int m = 0; m < MR; m++) {
#pragma unroll
    for (int n = 0; n < NR; n++) {
      const int row = m0 + wr * (MR * 16) + m * 16 + g * 4;
      const int col = n0 + wc * (NR * 16) + n * 16 + lr;
      const float bv = BIAS ? bias[col] : 0.f;
#pragma unroll
      for (int r = 0; r < 4; r++) {
        float v = acc[m][n][r] + bv;
        if (RELU) v = fmaxf(v, 0.f);
        if (OUTF) ((float*)C)[(long)z * sCz + (long)(row + r) * ldc + col] = v;
        else ((bf16*)C)[(long)z * sCz + (long)(row + r) * ldc + col] = __float2bfloat16(v);
      }
    }
  }
}

// ---------- flash attention, both sets in one launch; O overwrites Q cols in qkv ----------
__global__ __launch_bounds__(256) void flash_kernel(bf16* __restrict__ qkv,
                                                    const bf16* __restrict__ vtb) {
  __shared__ bf16 Qs[64 * 64], Ks[64 * 64], Vs[64 * 64];
  __shared__ bf16 Ps[4][16 * 64];
  const int tid = threadIdx.x;
  const int lane = tid & 63, wave = tid >> 6;
  const int g = lane >> 4, lr = lane & 15;
  const int qt = blockIdx.x & 15;
  const int bh = (blockIdx.x >> 4) & 63;
  const int set = blockIdx.x >> 10;
  const int b = bh >> 3, h = bh & 7;

  bf16* Qp = qkv + (long)b * S_ * QKVLD + set * 1536 + h * DH_;
  const bf16* Kp = Qp + 512;
  const bf16* Vp = vtb + ((long)(set * 64 + bh)) * DH_ * S_;

  // hand-rolled staging geometry: 256 thr x 16B = 32 rows/pass, 2 passes per 64-row tile
  const int sr = tid >> 3;                 // row 0..31
  const int scb = (tid & 7) << 4;          // dest byte col
  const int sb = scb ^ ((sr & 7) << 4);    // swizzled source byte col ((sr+32)&7 == sr&7)
  char* qDst = (char*)Qs + sr * 128 + scb;
  char* kDst = (char*)Ks + sr * 128 + scb;
  char* vDst = (char*)Vs + sr * 128 + scb;
  const bf16* qSrc = Qp + (long)(qt * 64 + sr) * QKVLD + (sb >> 1);
  const bf16* kSrc = Kp + (long)sr * QKVLD + (sb >> 1);
  const bf16* vSrc = Vp + (long)sr * S_ + (sb >> 1);

  async_copy16(qSrc, qDst);
  async_copy16(qSrc + 32 * QKVLD, qDst + 4096);
  async_copy16(kSrc, kDst);
  async_copy16(kSrc + 32 * QKVLD, kDst + 4096);
  async_copy16(vSrc, vDst);
  async_copy16(vSrc + 32 * S_, vDst + 4096);
  __syncthreads();

  const bf16x8 qF0 = lds_frag(Qs, wave * 16 + lr, g * 8);
  const bf16x8 qF1 = lds_frag(Qs, wave * 16 + lr, 32 + g * 8);

  f32x4 oAcc[4];
#pragma unroll
  for (int n = 0; n < 4; n++) oAcc[n] = (f32x4){0.f, 0.f, 0.f, 0.f};
  float mrun[4], lrun[4];
#pragma unroll
  for (int r = 0; r < 4; r++) { mrun[r] = -INFINITY; lrun[r] = 0.f; }

  const float c = 0.125f * 1.44269504f;  // (1/sqrt(DH)) * log2(e)

  for (int kt0 = 0; kt0 < S_; kt0 += 64) {
    f32x4 sAcc[4];
#pragma unroll
    for (int n = 0; n < 4; n++) sAcc[n] = (f32x4){0.f, 0.f, 0.f, 0.f};
    __builtin_amdgcn_s_setprio(1);
#pragma unroll
    for (int ks = 0; ks < 64; ks += 32) {
      const bf16x8 qF = ks ? qF1 : qF0;
#pragma unroll
      for (int n = 0; n < 4; n++) {
        bf16x8 kF = lds_frag(Ks, n * 16 + lr, ks + g * 8);
        sAcc[n] = __builtin_amdgcn_mfma_f32_16x16x32_bf16(qF, kF, sAcc[n], 0, 0, 0);
      }
    }
    __builtin_amdgcn_s_setprio(0);

    // softmax in log2 domain
#pragma unroll
    for (int n = 0; n < 4; n++) sAcc[n] = sAcc[n] * c;
    float mx[4];
#pragma unroll
    for (int r = 0; r < 4; r++) {
      mx[r] = fmaxf(fmaxf(sAcc[0][r], sAcc[1][r]), fmaxf(sAcc[2][r], sAcc[3][r]));
#pragma unroll
      for (int d = 1; d < 16; d <<= 1) mx[r] = fmaxf(mx[r], __shfl_xor(mx[r], d, 64));
    }
    float growth = 0.f;
#pragma unroll
    for (int r = 0; r < 4; r++) growth = fmaxf(growth, mx[r] - mrun[r]);
    if (!__all(growth <= 11.5f)) {   // defer-rescale: p bounded by 2^11.5
#pragma unroll
      for (int r = 0; r < 4; r++) {
        const float mnew = fmaxf(mrun[r], mx[r]);
        const float resc = exp2f(mrun[r] - mnew);
#pragma unroll
        for (int n = 0; n < 4; n++) oAcc[n][r] *= resc;
        lrun[r] *= resc;
        mrun[r] = mnew;
      }
    }
    float p[4][4];
#pragma unroll
    for (int r = 0; r < 4; r++) {
      float s = 0.f;
#pragma unroll
      for (int n = 0; n < 4; n++) {
        p[n][r] = exp2f(sAcc[n][r] - mrun[r]);
        s += p[n][r];
      }
#pragma unroll
      for (int d = 1; d < 16; d <<= 1) s += __shfl_xor(s, d, 64);
      lrun[r] += s;
    }

    // P -> per-wave LDS (bf16), swizzled
    bf16* Pw = Ps[wave];
#pragma unroll
    for (int n = 0; n < 4; n++)
#pragma unroll
      for (int r = 0; r < 4; r++) {
        const int q = g * 4 + r;
        const int key = n * 16 + lr;
        const int byte = (q << 7) + ((key << 1) ^ ((q & 7) << 4));
        *(bf16*)((char*)Pw + byte) = __float2bfloat16(p[n][r]);
      }

    // PV
    __builtin_amdgcn_s_setprio(1);
#pragma unroll
    for (int ks = 0; ks < 64; ks += 32) {
      bf16x8 pF = lds_frag(Pw, lr, ks + g * 8);
#pragma unroll
      for (int n = 0; n < 4; n++) {
        bf16x8 vF = lds_frag(Vs, n * 16 + lr, ks + g * 8);
        oAcc[n] = __builtin_amdgcn_mfma_f32_16x16x32_bf16(pF, vF, oAcc[n], 0, 0, 0);
      }
    }
    __builtin_amdgcn_s_setprio(0);
    __syncthreads();   // all waves done with Ks/Vs
    if (kt0 + 64 < S_) {
      kSrc += 64 * QKVLD;
      vSrc += 64;
      async_copy16(kSrc, kDst);
      async_copy16(kSrc + 32 * QKVLD, kDst + 4096);
      async_copy16(vSrc, vDst);
      async_copy16(vSrc + 32 * S_, vDst + 4096);
    }
    __syncthreads();   // staged tile visible
  }

  // O overwrites this block's own Q region (already consumed into qF0/qF1)
#pragma unroll
  for (int r = 0; r < 4; r++) {
    const float inv = 1.f / lrun[r];
    const int s = qt * 64 + wave * 16 + g * 4 + r;
    bf16* op = Qp + (long)s * QKVLD;
#pragma unroll
    for (int n = 0; n < 4; n++) op[n * 16 + lr] = __float2bfloat16(oAcc[n][r] * inv);
  }
}

// ---------- fuse1: xlnB = bf16(LN(x + gather(attn1+attn2))) ----------
__global__ __launch_bounds__(256) void fuse1_kernel(const float* __restrict__ x,
                                                    const float* __restrict__ a1,
                                                    const float* __restrict__ a2,
                                                    const int* __restrict__ idx,
                                                    const int* __restrict__ Np,
                                                    const float* __restrict__ gw,
                                                    const float* __restrict__ bw,
                                                    bf16* __restrict__ xlnB) {
  const int N = *Np;
  const int row = blockIdx.x * 4 + (threadIdx.x >> 6);
  const int lane = threadIdx.x & 63;
  const int b = row >> 10, s = row & 1023;
  const int j = (s < N) ? idx[b * NV_ + s] : s;
  const float* xp = x + (long)row * D_ + lane * 8;
  const float* p1 = a1 + ((long)b * S_ + j) * D_ + lane * 8;
  const float* p2 = a2 + ((long)b * S_ + j) * D_ + lane * 8;
  float v[8];
  float sum = 0.f;
#pragma unroll
  for (int q = 0; q < 2; q++) {
    const float4 t = ((const float4*)xp)[q];
    const float4 u = ((const float4*)p1)[q];
    const float4 w = ((const float4*)p2)[q];
    v[q * 4 + 0] = t.x + u.x + w.x; v[q * 4 + 1] = t.y + u.y + w.y;
    v[q * 4 + 2] = t.z + u.z + w.z; v[q * 4 + 3] = t.w + u.w + w.w;
  }
#pragma unroll
  for (int i = 0; i < 8; i++) sum += v[i];
#pragma unroll
  for (int o = 1; o < 64; o <<= 1) sum += __shfl_xor(sum, o, 64);
  const float mu = sum * (1.f / D_);
  float var = 0.f;
#pragma unroll
  for (int i = 0; i < 8; i++) { const float t = v[i] - mu; var += t * t; }
#pragma unroll
  for (int o = 1; o < 64; o <<= 1) var += __shfl_xor(var, o, 64);
  const float rs = rsqrtf(var * (1.f / D_) + 1e-5f);
#pragma unroll
  for (int i = 0; i < 8; i++) {
    const int d = lane * 8 + i;
    xlnB[(long)row * D_ + d] = __float2bfloat16((v[i] - mu) * rs * gw[d] + bw[d]);
  }
}

// ---------- fuse2: out = LN(xln + y) ----------
__global__ __launch_bounds__(256) void fuse2_kernel(const bf16* __restrict__ xlnB,
                                                    const bf16* __restrict__ ybf,
                                                    const float* __restrict__ gw,
                                                    const float* __restrict__ bw,
                                                    float* __restrict__ out) {
  const int row = blockIdx.x * 4 + (threadIdx.x >> 6);
  const int lane = threadIdx.x & 63;
  const bf16* xp = xlnB + (long)row * D_ + lane * 8;
  const bf16* yp = ybf + (long)row * D_ + lane * 8;
  float v[8];
  float sum = 0.f;
#pragma unroll
  for (int i = 0; i < 8; i++) {
    v[i] = __bfloat162float(xp[i]) + __bfloat162float(yp[i]);
    sum += v[i];
  }
#pragma unroll
  for (int o = 1; o < 64; o <<= 1) sum += __shfl_xor(sum, o, 64);
  const float mu = sum * (1.f / D_);
  float var = 0.f;
#pragma unroll
  for (int i = 0; i < 8; i++) { const float t = v[i] - mu; var += t * t; }
#pragma unroll
  for (int o = 1; o < 64; o <<= 1) var += __shfl_xor(var, o, 64);
  const float rs = rsqrtf(var * (1.f / D_) + 1e-5f);
#pragma unroll
  for (int i = 0; i < 8; i++) {
    const int d = lane * 8 + i;
    out[(long)row * D_ + d] = (v[i] - mu) * rs * gw[d] + bw[d];
  }
}

extern "C" void kernel_launch(void* const* d_in, const int* in_sizes, int n_in,
                              void* d_out, int out_size, void* d_ws, size_t ws_size,
                              hipStream_t stream) {
  const float* x   = (const float*)d_in[0];
  const int* idx1  = (const int*)d_in[1];
  const int* idx2  = (const int*)d_in[2];
  const int* Np    = (const int*)d_in[3];
  const float* b_conv1 = (const float*)d_in[13];
  const float* b_conv2 = (const float*)d_in[15];
  const float* g1    = (const float*)d_in[16];
  const float* beta1 = (const float*)d_in[17];
  const float* g2    = (const float*)d_in[18];
  const float* beta2 = (const float*)d_in[19];

  float* outp  = (float*)d_out;
  float* attn1 = outp + BSD_;

  // workspace layout (peak 72 MB)
  const size_t DD = (size_t)D_ * D_;
  char* w = (char*)d_ws;
  bf16* wT  = (bf16*)w;                          // 8*DD bf16 = 4MB  [0,4M): q1,k1,v1,q2,k2,v2,o1,o2
  bf16* w1T = wT + 8 * DD;                       // [DF][D] 2MB      [4M,6M)
  bf16* w2T = w1T + (size_t)DF_ * D_;            // [D][DF] 2MB      [6M,8M)
  bf16* qkv = (bf16*)(w + (8ll << 20));          // [8192][3072] 48MB [8M,56M); Q cols become O
  bf16* xl1 = (bf16*)(w + (56ll << 20));         // 8MB [56M,64M) (dead after QKV GEMM)
  bf16* vtb = (bf16*)(w + (56ll << 20));         // 16MB [56M,72M) (overwrites dead xl1)
  bf16* xlnB = (bf16*)(w + (56ll << 20));        // 8MB (overwrites dead vtb)
  bf16* ffn = (bf16*)(w + (8ll << 20));          // [8192][2048] 32MB (overwrites dead qkv)
  bf16* ybf = (bf16*)(w + (40ll << 20));         // 8MB [40M,48M)

  WP8 wp;
  wp.p[0] = (const float*)d_in[4];   // Wq1
  wp.p[1] = (const float*)d_in[5];   // Wk1
  wp.p[2] = (const float*)d_in[6];   // Wv1
  wp.p[3] = (const float*)d_in[8];   // Wq2
  wp.p[4] = (const float*)d_in[9];   // Wk2
  wp.p[5] = (const float*)d_in[10];  // Wv2
  wp.p[6] = (const float*)d_in[7];   // Wo1
  wp.p[7] = (const float*)d_in[11];  // Wo2

  const dim3 tb(32, 8);
  wtrans8_kernel<<<dim3(16, 16, 8), tb, 0, stream>>>(wp, wT);
  wtrans_kernel<<<dim3(DF_ / 32, D_ / 32), tb, 0, stream>>>((const float*)d_in[12], w1T, D_, DF_);
  wtrans_kernel<<<dim3(D_ / 32, DF_ / 32), tb, 0, stream>>>((const float*)d_in[14], w2T, DF_, D_);

  gather_cvt_kernel<<<BS_ / 2, 256, 0, stream>>>(x, idx1, Np, xl1);

  // fused QKV for both sets: [8192,512] x [3072,512]^T -> qkv [8192,3072]
  gemm_bt<128, 128, 4, 4, 0, 0, 0><<<dim3(BS_ / 128, QKVLD / 128, 1), 256, 0, stream>>>(
      xl1, D_, 0, wT, 0, nullptr, qkv, QKVLD, 0, D_);

  vtrans_kernel<<<dim3(S_ / 32, DH_ / 32, 128), tb, 0, stream>>>(qkv, vtb);

  // flash over both sets (2048 blocks); O written in-place over Q columns
  flash_kernel<<<2 * B_ * H_ * (S_ / 64), 256, 0, stream>>>(qkv, vtb);

  // Wo GEMMs batched z=2: A = qkv Q-cols (lda 3072), out fp32 attn1/attn2
  gemm_bt<128, 64, 4, 2, 1, 0, 0><<<dim3(BS_ / 128, D_ / 64, 2), 256, 0, stream>>>(
      qkv, QKVLD, 1536, wT + 6 * DD, (long)DD, nullptr, attn1, D_, (long)BSD_, D_);

  fuse1_kernel<<<BS_ / 4, 256, 0, stream>>>(x, attn1, attn1 + BSD_, idx2, Np, g1, beta1, xlnB);

  gemm_bt<128, 128, 4, 4, 0, 1, 1><<<dim3(BS_ / 128, DF_ / 128, 1), 256, 0, stream>>>(
      xlnB, D_, 0, w1T, 0, b_conv1, ffn, DF_, 0, D_);
  gemm_bt<128, 64, 4, 2, 0, 1, 0><<<dim3(BS_ / 128, D_ / 64, 1), 256, 0, stream>>>(
      ffn, DF_, 0, w2T, 0, b_conv2, ybf, D_, 0, DF_);

  fuse2_kernel<<<BS_ / 4, 256, 0, stream>>>(xlnB, ybf, g2, beta2, outp);
}

// Round 4
// 217.288 us; speedup vs baseline: 1.6204x; 1.2212x over previous
//
#include <hip/hip_runtime.h>
#include <hip/hip_bf16.h>
#include <stdint.h>

#define B_ 8
#define S_ 1024
#define NV_ 768
#define D_ 512
#define DF_ 2048
#define H_ 8
#define DH_ 64
#define BS_ (B_*S_)
#define BSD_ ((size_t)B_*S_*D_)
#define QKVLD 3072

typedef __bf16 bf16x8 __attribute__((ext_vector_type(8)));
typedef __bf16 bf16x4v __attribute__((ext_vector_type(4)));
typedef float f32x4 __attribute__((ext_vector_type(4)));
typedef float f32x16 __attribute__((ext_vector_type(16)));
typedef __hip_bfloat16 bf16;

__device__ __forceinline__ void async_copy16(const void* g, void* l) {
  __builtin_amdgcn_global_load_lds((const __attribute__((address_space(1))) void*)g,
                                   (__attribute__((address_space(3))) void*)l, 16, 0, 0);
}

// Stage a tile of `rows` x 64 bf16 columns into LDS (row-major 128B rows).
// XOR swizzle byte ^= (row&7)<<4 applied on the GLOBAL source address
// (linear LDS dest + inverse-swizzled source + swizzled read).
__device__ __forceinline__ void stage_tile(const bf16* __restrict__ g, int gRow0, long ldg,
                                           int gCol0, bf16* lds, int rows, int tid) {
  const int totalBytes = rows << 7;
  for (int off = tid * 16; off < totalBytes; off += 4096) {
    const int r = off >> 7;
    const int c = off & 127;
    const int srcByte = c ^ ((r & 7) << 4);
    const bf16* gp = g + (long)(gRow0 + r) * ldg + gCol0 + (srcByte >> 1);
    async_copy16(gp, (char*)lds + off);
  }
}

// Read an 8-element (16B) MFMA fragment at (row, kElem..kElem+7)
__device__ __forceinline__ bf16x8 lds_frag(const bf16* base, int row, int kElem) {
  const int byte = (row << 7) + ((kElem << 1) ^ ((row & 7) << 4));
  return *(const bf16x8*)((const char*)base + byte);
}

// V^T fragment for PV key-window f(hi,e) = (e&3)+8*(e>>2)+c0 : two b64 reads
// at cols c0..c0+3 and c0+8..c0+11 of swizzled row.
__device__ __forceinline__ bf16x8 v_frag(const bf16* base, int row, int c0) {
  const char* p = (const char*)base + (row << 7);
  const int swz = (row & 7) << 4;
  union { bf16x4v v[2]; bf16x8 b; } r;
  r.v[0] = *(const bf16x4v*)(p + (((c0) << 1) ^ swz));
  r.v[1] = *(const bf16x4v*)(p + (((c0 + 8) << 1) ^ swz));
  return r.b;
}

// A-fragment for PV directly from 8 consecutive exp'd score registers.
template<int BASE>
__device__ __forceinline__ bf16x8 p_frag(const f32x16& s) {
  union { ushort u[8]; bf16x8 b; } r;
#pragma unroll
  for (int e = 0; e < 8; e++)
    r.u[e] = __bfloat16_as_ushort(__float2bfloat16(s[BASE + e]));
  return r.b;
}

__device__ __forceinline__ f32x16 zero16() {
  f32x16 z;
#pragma unroll
  for (int i = 0; i < 16; i++) z[i] = 0.f;
  return z;
}

// ---------- 8x weight transpose+convert (512x512); Wq entries pre-scaled ----------
struct WP8 { const float* p[8]; };
__global__ __launch_bounds__(256) void wtrans8_kernel(WP8 ws, bf16* __restrict__ dstBase) {
  __shared__ float tile[32][33];
  const int z = blockIdx.z;
  const float sc = (z == 0 || z == 3) ? 0.1803368801f : 1.f;  // 0.125*log2(e) into Wq
  const float* __restrict__ src = ws.p[z];
  bf16* __restrict__ dst = dstBase + (size_t)z * D_ * D_;
  const int tx = threadIdx.x, ty = threadIdx.y;
  const int n0 = blockIdx.x * 32, k0 = blockIdx.y * 32;
#pragma unroll
  for (int i = 0; i < 4; i++) tile[ty + i * 8][tx] = src[(long)(k0 + ty + i * 8) * D_ + n0 + tx];
  __syncthreads();
#pragma unroll
  for (int i = 0; i < 4; i++)
    dst[(long)(n0 + ty + i * 8) * D_ + k0 + tx] = __float2bfloat16(tile[tx][ty + i * 8] * sc);
}

// ---------- generic weight transpose+convert ----------
__global__ __launch_bounds__(256) void wtrans_kernel(const float* __restrict__ src,
                                                     bf16* __restrict__ dst, int K, int N) {
  __shared__ float tile[32][33];
  const int tx = threadIdx.x, ty = threadIdx.y;
  const int n0 = blockIdx.x * 32, k0 = blockIdx.y * 32;
#pragma unroll
  for (int i = 0; i < 4; i++) tile[ty + i * 8][tx] = src[(long)(k0 + ty + i * 8) * N + n0 + tx];
  __syncthreads();
#pragma unroll
  for (int i = 0; i < 4; i++)
    dst[(long)(n0 + ty + i * 8) * K + k0 + tx] = __float2bfloat16(tile[tx][ty + i * 8]);
}

// ---------- V transpose out of qkv -> (set,b,h)[DH][S] ----------
__global__ __launch_bounds__(256) void vtrans_kernel(const bf16* __restrict__ qkv,
                                                     bf16* __restrict__ vtb) {
  __shared__ bf16 tile[32][33];
  const int tx = threadIdx.x, ty = threadIdx.y;
  const int s0 = blockIdx.x * 32, d0 = blockIdx.y * 32;
  const int z = blockIdx.z;               // 0..127: set*64 + b*8 + h
  const int set = z >> 6, bh = z & 63;
  const bf16* sp = qkv + (long)(bh >> 3) * S_ * QKVLD + set * 1536 + 1024 + (bh & 7) * 64;
  bf16* dp = vtb + (long)z * DH_ * S_;
#pragma unroll
  for (int i = 0; i < 4; i++) tile[ty + i * 8][tx] = sp[(long)(s0 + ty + i * 8) * QKVLD + d0 + tx];
  __syncthreads();
#pragma unroll
  for (int i = 0; i < 4; i++) dp[(long)(d0 + ty + i * 8) * S_ + s0 + tx] = tile[tx][ty + i * 8];
}

// ---------- gather + fp32->bf16 ----------
__global__ __launch_bounds__(256) void gather_cvt_kernel(const float* __restrict__ x,
                                                         const int* __restrict__ idx,
                                                         const int* __restrict__ Np,
                                                         bf16* __restrict__ out) {
  const int N = *Np;
  const int row = blockIdx.x * 2 + (threadIdx.x >> 7);
  const int t = threadIdx.x & 127;
  const int b = row >> 10, s = row & 1023;
  const int src = (s < N) ? idx[b * NV_ + s] : s;
  const float4 v = *(const float4*)(x + ((long)b * S_ + src) * D_ + t * 4);
  ushort4 u;
  u.x = (ushort)__bfloat16_as_ushort(__float2bfloat16(v.x));
  u.y = (ushort)__bfloat16_as_ushort(__float2bfloat16(v.y));
  u.z = (ushort)__bfloat16_as_ushort(__float2bfloat16(v.z));
  u.w = (ushort)__bfloat16_as_ushort(__float2bfloat16(v.w));
  *(ushort4*)(out + (long)row * D_ + t * 4) = u;
}

// ---------- GEMM: C[M,N] = A[M,K] * Bt[N,K]^T (+bias)(+relu) ----------
template<int BM, int BN, int MR, int NR, int OUTF, int BIAS, int RELU>
__global__ __launch_bounds__(256) void gemm_bt(const bf16* __restrict__ A, long lda, long sAz,
                                               const bf16* __restrict__ Bt, long sBz,
                                               const float* __restrict__ bias,
                                               void* __restrict__ C, long ldc, long sCz,
                                               int K) {
  constexpr int WC = BN / (NR * 16);
  constexpr int WR = BM / (MR * 16);
  static_assert(WR * WC == 4, "4 waves");
  __shared__ bf16 As[BM * 64];
  __shared__ bf16 Bs[BN * 64];
  const int tid = threadIdx.x;
  const int lane = tid & 63, wave = tid >> 6;
  const int wr = wave / WC, wc = wave % WC;
  const int g = lane >> 4, lr = lane & 15;
  const int m0 = blockIdx.x * BM, n0 = blockIdx.y * BN;
  const int z = blockIdx.z;
  A += (long)z * sAz;
  Bt += (long)z * sBz;

  f32x4 acc[MR][NR];
#pragma unroll
  for (int m = 0; m < MR; m++)
#pragma unroll
    for (int n = 0; n < NR; n++) acc[m][n] = (f32x4){0.f, 0.f, 0.f, 0.f};

  for (int kt = 0; kt < K; kt += 64) {
    stage_tile(A, m0, lda, kt, As, BM, tid);
    stage_tile(Bt, n0, K, kt, Bs, BN, tid);
    __syncthreads();
#pragma unroll
    for (int ks = 0; ks < 64; ks += 32) {
      const int kk = ks + g * 8;
      bf16x8 aF[MR], bF[NR];
#pragma unroll
      for (int m = 0; m < MR; m++) aF[m] = lds_frag(As, wr * (MR * 16) + m * 16 + lr, kk);
#pragma unroll
      for (int n = 0; n < NR; n++) bF[n] = lds_frag(Bs, wc * (NR * 16) + n * 16 + lr, kk);
#pragma unroll
      for (int m = 0; m < MR; m++)
#pragma unroll
        for (int n = 0; n < NR; n++)
          acc[m][n] = __builtin_amdgcn_mfma_f32_16x16x32_bf16(aF[m], bF[n], acc[m][n], 0, 0, 0);
    }
    __syncthreads();
  }

#pragma unroll
  for (int m = 0; m < MR; m++) {
#pragma unroll
    for (int n = 0; n < NR; n++) {
      const int row = m0 + wr * (MR * 16) + m * 16 + g * 4;
      const int col = n0 + wc * (NR * 16) + n * 16 + lr;
      const float bv = BIAS ? bias[col] : 0.f;
#pragma unroll
      for (int r = 0; r < 4; r++) {
        float v = acc[m][n][r] + bv;
        if (RELU) v = fmaxf(v, 0.f);
        if (OUTF) ((float*)C)[(long)z * sCz + (long)(row + r) * ldc + col] = v;
        else ((bf16*)C)[(long)z * sCz + (long)(row + r) * ldc + col] = __float2bfloat16(v);
      }
    }
  }
}

// ---------- flash attention: swapped-QK 32x32, 4 warps x 32q, KVBLK=64 ----------
// Scores arrive pre-scaled in log2 units (scale folded into Wq).
// Lane (q=lane&31, hi=lane>>5) holds S^T values for its q at keys crow(r,hi).
// PV uses k-slot freedom: consecutive score regs form the A fragment for key
// window f(hi,e)=(e&3)+8*(e>>2)+4*hi; V^T fragment reads matching columns.
__global__ __launch_bounds__(256, 4) void flash_kernel(bf16* __restrict__ qkv,
                                                       const bf16* __restrict__ vtb) {
  __shared__ bf16 Qs[128 * 64];   // 16KB
  __shared__ bf16 Ks[64 * 64];    // 8KB
  __shared__ bf16 Vs[64 * 64];    // 8KB (V^T tile: rows=d, cols=k)
  const int tid = threadIdx.x;
  const int lane = tid & 63, warp = tid >> 6;
  const int qlo = lane & 31, hi = lane >> 5;

  // bijective XCD swizzle: each XCD gets 128 consecutive swz ids
  const int bid = (int)blockIdx.x;
  const int swz = (bid & 7) * 128 + (bid >> 3);
  const int qt = swz & 7;                 // 8 q-tiles of 128 rows
  const int sbh = swz >> 3;               // set*64 + b*8 + h
  const int set = sbh >> 6;
  const int b = (sbh >> 3) & 7, h = sbh & 7;

  bf16* Qp = qkv + (long)b * S_ * QKVLD + set * 1536 + h * DH_;
  const bf16* Kp = Qp + 512;
  const bf16* Vp = vtb + (long)sbh * DH_ * S_;

  stage_tile(Qp, qt * 128, QKVLD, 0, Qs, 128, tid);
  stage_tile(Kp, 0, QKVLD, 0, Ks, 64, tid);
  stage_tile(Vp, 0, S_, 0, Vs, 64, tid);
  __syncthreads();

  // hoist Q fragments (Qs is never overwritten)
  bf16x8 qFh[4];
#pragma unroll
  for (int d4 = 0; d4 < 4; d4++) qFh[d4] = lds_frag(Qs, warp * 32 + qlo, d4 * 16 + hi * 8);

  f32x16 oAcc0 = zero16(), oAcc1 = zero16();
  float mrun = -INFINITY, lrun = 0.f;

  for (int kt0 = 0; kt0 < S_; kt0 += 64) {
    // QK^T swapped: S^T[key][q] = K-tile . Q^T  (2 subtiles of 32 keys)
    f32x16 s0 = zero16(), s1 = zero16();
    __builtin_amdgcn_s_setprio(1);
#pragma unroll
    for (int d4 = 0; d4 < 4; d4++) {
      const int kc = d4 * 16 + hi * 8;
      bf16x8 kF0 = lds_frag(Ks, qlo, kc);
      bf16x8 kF1 = lds_frag(Ks, 32 + qlo, kc);
      s0 = __builtin_amdgcn_mfma_f32_32x32x16_bf16(kF0, qFh[d4], s0, 0, 0, 0);
      s1 = __builtin_amdgcn_mfma_f32_32x32x16_bf16(kF1, qFh[d4], s1, 0, 0, 0);
    }
    __builtin_amdgcn_s_setprio(0);

    // row max: in-lane over 32 held scores + cross-half shfl
    float mx = s0[0];
#pragma unroll
    for (int r = 1; r < 16; r++) mx = fmaxf(mx, s0[r]);
#pragma unroll
    for (int r = 0; r < 16; r++) mx = fmaxf(mx, s1[r]);
    mx = fmaxf(mx, __shfl_xor(mx, 32, 64));

    if (!__all(mx - mrun <= 11.5f)) {   // defer-rescale (log2 domain)
      const float mnew = fmaxf(mrun, mx);
      const float resc = exp2f(mrun - mnew);
      mrun = mnew;
      lrun *= resc;
#pragma unroll
      for (int r = 0; r < 16; r++) {
        const float rs = __shfl(resc, (r & 3) + 8 * (r >> 2) + 4 * hi, 64);
        oAcc0[r] *= rs;
        oAcc1[r] *= rs;
      }
    }

#pragma unroll
    for (int r = 0; r < 16; r++) s0[r] = exp2f(s0[r] - mrun);
#pragma unroll
    for (int r = 0; r < 16; r++) s1[r] = exp2f(s1[r] - mrun);

    float sm = 0.f;
#pragma unroll
    for (int r = 0; r < 16; r++) sm += s0[r] + s1[r];
    lrun += sm + __shfl_xor(sm, 32, 64);

    // PV: O[q][d] += P . V ; A = consecutive score regs, B = matching V^T cols
    __builtin_amdgcn_s_setprio(1);
    {
      const bf16x8 pa0 = p_frag<0>(s0);
      oAcc0 = __builtin_amdgcn_mfma_f32_32x32x16_bf16(pa0, v_frag(Vs, qlo, 4 * hi), oAcc0, 0, 0, 0);
      oAcc1 = __builtin_amdgcn_mfma_f32_32x32x16_bf16(pa0, v_frag(Vs, 32 + qlo, 4 * hi), oAcc1, 0, 0, 0);
      const bf16x8 pa1 = p_frag<8>(s0);
      oAcc0 = __builtin_amdgcn_mfma_f32_32x32x16_bf16(pa1, v_frag(Vs, qlo, 16 + 4 * hi), oAcc0, 0, 0, 0);
      oAcc1 = __builtin_amdgcn_mfma_f32_32x32x16_bf16(pa1, v_frag(Vs, 32 + qlo, 16 + 4 * hi), oAcc1, 0, 0, 0);
      const bf16x8 pa2 = p_frag<0>(s1);
      oAcc0 = __builtin_amdgcn_mfma_f32_32x32x16_bf16(pa2, v_frag(Vs, qlo, 32 + 4 * hi), oAcc0, 0, 0, 0);
      oAcc1 = __builtin_amdgcn_mfma_f32_32x32x16_bf16(pa2, v_frag(Vs, 32 + qlo, 32 + 4 * hi), oAcc1, 0, 0, 0);
      const bf16x8 pa3 = p_frag<8>(s1);
      oAcc0 = __builtin_amdgcn_mfma_f32_32x32x16_bf16(pa3, v_frag(Vs, qlo, 48 + 4 * hi), oAcc0, 0, 0, 0);
      oAcc1 = __builtin_amdgcn_mfma_f32_32x32x16_bf16(pa3, v_frag(Vs, 32 + qlo, 48 + 4 * hi), oAcc1, 0, 0, 0);
    }
    __builtin_amdgcn_s_setprio(0);

    __syncthreads();
    if (kt0 + 64 < S_) {
      stage_tile(Kp, kt0 + 64, QKVLD, 0, Ks, 64, tid);
      stage_tile(Vp, 0, S_, kt0 + 64, Vs, 64, tid);
    }
    __syncthreads();
  }

  // epilogue: per-row normalize via shfl broadcast; O overwrites Q columns
#pragma unroll
  for (int r = 0; r < 16; r++) {
    const int q = (r & 3) + 8 * (r >> 2) + 4 * hi;
    const float linv = 1.f / __shfl(lrun, q, 64);
    bf16* op = Qp + (long)(qt * 128 + warp * 32 + q) * QKVLD;
    op[qlo] = __float2bfloat16(oAcc0[r] * linv);
    op[32 + qlo] = __float2bfloat16(oAcc1[r] * linv);
  }
}

// ---------- fuse1: xlnB = bf16(LN(x + gather(attn1+attn2))) ----------
__global__ __launch_bounds__(256) void fuse1_kernel(const float* __restrict__ x,
                                                    const float* __restrict__ a1,
                                                    const float* __restrict__ a2,
                                                    const int* __restrict__ idx,
                                                    const int* __restrict__ Np,
                                                    const float* __restrict__ gw,
                                                    const float* __restrict__ bw,
                                                    bf16* __restrict__ xlnB) {
  const int N = *Np;
  const int row = blockIdx.x * 4 + (threadIdx.x >> 6);
  const int lane = threadIdx.x & 63;
  const int b = row >> 10, s = row & 1023;
  const int j = (s < N) ? idx[b * NV_ + s] : s;
  const float* xp = x + (long)row * D_ + lane * 8;
  const float* p1 = a1 + ((long)b * S_ + j) * D_ + lane * 8;
  const float* p2 = a2 + ((long)b * S_ + j) * D_ + lane * 8;
  float v[8];
  float sum = 0.f;
#pragma unroll
  for (int q = 0; q < 2; q++) {
    const float4 t = ((const float4*)xp)[q];
    const float4 u = ((const float4*)p1)[q];
    const float4 w = ((const float4*)p2)[q];
    v[q * 4 + 0] = t.x + u.x + w.x; v[q * 4 + 1] = t.y + u.y + w.y;
    v[q * 4 + 2] = t.z + u.z + w.z; v[q * 4 + 3] = t.w + u.w + w.w;
  }
#pragma unroll
  for (int i = 0; i < 8; i++) sum += v[i];
#pragma unroll
  for (int o = 1; o < 64; o <<= 1) sum += __shfl_xor(sum, o, 64);
  const float mu = sum * (1.f / D_);
  float var = 0.f;
#pragma unroll
  for (int i = 0; i < 8; i++) { const float t = v[i] - mu; var += t * t; }
#pragma unroll
  for (int o = 1; o < 64; o <<= 1) var += __shfl_xor(var, o, 64);
  const float rs = rsqrtf(var * (1.f / D_) + 1e-5f);
#pragma unroll
  for (int i = 0; i < 8; i++) {
    const int d = lane * 8 + i;
    xlnB[(long)row * D_ + d] = __float2bfloat16((v[i] - mu) * rs * gw[d] + bw[d]);
  }
}

// ---------- fuse2: out = LN(xln + y) ----------
__global__ __launch_bounds__(256) void fuse2_kernel(const bf16* __restrict__ xlnB,
                                                    const bf16* __restrict__ ybf,
                                                    const float* __restrict__ gw,
                                                    const float* __restrict__ bw,
                                                    float* __restrict__ out) {
  const int row = blockIdx.x * 4 + (threadIdx.x >> 6);
  const int lane = threadIdx.x & 63;
  const bf16* xp = xlnB + (long)row * D_ + lane * 8;
  const bf16* yp = ybf + (long)row * D_ + lane * 8;
  float v[8];
  float sum = 0.f;
#pragma unroll
  for (int i = 0; i < 8; i++) {
    v[i] = __bfloat162float(xp[i]) + __bfloat162float(yp[i]);
    sum += v[i];
  }
#pragma unroll
  for (int o = 1; o < 64; o <<= 1) sum += __shfl_xor(sum, o, 64);
  const float mu = sum * (1.f / D_);
  float var = 0.f;
#pragma unroll
  for (int i = 0; i < 8; i++) { const float t = v[i] - mu; var += t * t; }
#pragma unroll
  for (int o = 1; o < 64; o <<= 1) var += __shfl_xor(var, o, 64);
  const float rs = rsqrtf(var * (1.f / D_) + 1e-5f);
#pragma unroll
  for (int i = 0; i < 8; i++) {
    const int d = lane * 8 + i;
    out[(long)row * D_ + d] = (v[i] - mu) * rs * gw[d] + bw[d];
  }
}

extern "C" void kernel_launch(void* const* d_in, const int* in_sizes, int n_in,
                              void* d_out, int out_size, void* d_ws, size_t ws_size,
                              hipStream_t stream) {
  const float* x   = (const float*)d_in[0];
  const int* idx1  = (const int*)d_in[1];
  const int* idx2  = (const int*)d_in[2];
  const int* Np    = (const int*)d_in[3];
  const float* b_conv1 = (const float*)d_in[13];
  const float* b_conv2 = (const float*)d_in[15];
  const float* g1    = (const float*)d_in[16];
  const float* beta1 = (const float*)d_in[17];
  const float* g2    = (const float*)d_in[18];
  const float* beta2 = (const float*)d_in[19];

  float* outp  = (float*)d_out;
  float* attn1 = outp + BSD_;

  // workspace layout (peak 72 MB)
  const size_t DD = (size_t)D_ * D_;
  char* w = (char*)d_ws;
  bf16* wT  = (bf16*)w;                          // 8*DD bf16 = 4MB: q1,k1,v1,q2,k2,v2,o1,o2
  bf16* w1T = wT + 8 * DD;                       // [DF][D] 2MB
  bf16* w2T = w1T + (size_t)DF_ * D_;            // [D][DF] 2MB
  bf16* qkv = (bf16*)(w + (8ll << 20));          // [8192][3072] 48MB; Q cols become O
  bf16* xl1 = (bf16*)(w + (56ll << 20));         // 8MB (dead after QKV GEMM)
  bf16* vtb = (bf16*)(w + (56ll << 20));         // 16MB (overwrites dead xl1)
  bf16* xlnB = (bf16*)(w + (56ll << 20));        // 8MB (overwrites dead vtb)
  bf16* ffn = (bf16*)(w + (8ll << 20));          // [8192][2048] 32MB (overwrites dead qkv)
  bf16* ybf = (bf16*)(w + (40ll << 20));         // 8MB

  WP8 wp;
  wp.p[0] = (const float*)d_in[4];   // Wq1 (scaled)
  wp.p[1] = (const float*)d_in[5];   // Wk1
  wp.p[2] = (const float*)d_in[6];   // Wv1
  wp.p[3] = (const float*)d_in[8];   // Wq2 (scaled)
  wp.p[4] = (const float*)d_in[9];   // Wk2
  wp.p[5] = (const float*)d_in[10];  // Wv2
  wp.p[6] = (const float*)d_in[7];   // Wo1
  wp.p[7] = (const float*)d_in[11];  // Wo2

  const dim3 tb(32, 8);
  wtrans8_kernel<<<dim3(16, 16, 8), tb, 0, stream>>>(wp, wT);
  wtrans_kernel<<<dim3(DF_ / 32, D_ / 32), tb, 0, stream>>>((const float*)d_in[12], w1T, D_, DF_);
  wtrans_kernel<<<dim3(D_ / 32, DF_ / 32), tb, 0, stream>>>((const float*)d_in[14], w2T, DF_, D_);

  gather_cvt_kernel<<<BS_ / 2, 256, 0, stream>>>(x, idx1, Np, xl1);

  // fused QKV for both sets: [8192,512] x [3072,512]^T -> qkv [8192,3072]
  gemm_bt<128, 128, 4, 4, 0, 0, 0><<<dim3(BS_ / 128, QKVLD / 128, 1), 256, 0, stream>>>(
      xl1, D_, 0, wT, 0, nullptr, qkv, QKVLD, 0, D_);

  vtrans_kernel<<<dim3(S_ / 32, DH_ / 32, 128), tb, 0, stream>>>(qkv, vtb);

  // flash: 128 sbh-units x 8 q-tiles = 1024 blocks; O in-place over Q columns
  flash_kernel<<<1024, 256, 0, stream>>>(qkv, vtb);

  // Wo GEMMs batched z=2: A = qkv Q-cols (lda 3072), out fp32 attn1/attn2
  gemm_bt<128, 64, 4, 2, 1, 0, 0><<<dim3(BS_ / 128, D_ / 64, 2), 256, 0, stream>>>(
      qkv, QKVLD, 1536, wT + 6 * DD, (long)DD, nullptr, attn1, D_, (long)BSD_, D_);

  fuse1_kernel<<<BS_ / 4, 256, 0, stream>>>(x, attn1, attn1 + BSD_, idx2, Np, g1, beta1, xlnB);

  gemm_bt<128, 128, 4, 4, 0, 1, 1><<<dim3(BS_ / 128, DF_ / 128, 1), 256, 0, stream>>>(
      xlnB, D_, 0, w1T, 0, b_conv1, ffn, DF_, 0, D_);
  gemm_bt<128, 64, 4, 2, 0, 1, 0><<<dim3(BS_ / 128, D_ / 64, 1), 256, 0, stream>>>(
      ffn, DF_, 0, w2T, 0, b_conv2, ybf, D_, 0, DF_);

  fuse2_kernel<<<BS_ / 4, 256, 0, stream>>>(xlnB, ybf, g2, beta2, outp);
}